// Round 1
// baseline (1246.463 us; speedup 1.0000x reference)
//
#include <hip/hip_runtime.h>
#include <math.h>

#define NGENES 978
#define EDIM   301
#define NNODES 10000
#define NEDGES 320000
#define NHEADS 4
// rep = 48/4 = 12 floats per (n,h,c) = 3 float4
#define F4_PER_NH (EDIM * 3)   // 903 float4 per (node, head)

// ---------------- index dtype detection (int32 vs int64) ----------------
// If edge_index is int64 (little-endian, values < 2^31), every odd 32-bit
// word is zero. With random values in [0,10000) an all-zero run of 64 odd
// words is impossible for int32.
__global__ void detect_idx64(const unsigned int* __restrict__ ei, int* flag) {
    int lane = threadIdx.x;  // 64 threads
    unsigned int v = ei[2 * lane + 1];
    unsigned long long nz = __ballot(v != 0u);
    if (lane == 0) *flag = (nz == 0ULL) ? 1 : 0;
}

__device__ __forceinline__ int load_idx(const void* ei, long long i, int is64) {
    return is64 ? (int)((const long long*)ei)[i] : ((const int*)ei)[i];
}

// ---------------- degree ----------------
__global__ void init_deg(float* deg) {
    int i = blockIdx.x * blockDim.x + threadIdx.x;
    if (i < NNODES) deg[i] = 1.0f;   // self-loop weight 1
}

__global__ void accum_deg(const void* __restrict__ ei, const float* __restrict__ w,
                          float* deg, const int* __restrict__ flag) {
    int i = blockIdx.x * blockDim.x + threadIdx.x;
    if (i >= NEDGES) return;
    int is64 = *flag;
    int d = load_idx(ei, (long long)NEDGES + i, is64);  // dst row
    atomicAdd(&deg[d], w[i]);
}

__global__ void compute_dinv(const float* __restrict__ deg, float* dinv) {
    int i = blockIdx.x * blockDim.x + threadIdx.x;
    if (i < NNODES) {
        float d = deg[i];
        dinv[i] = (d > 0.0f) ? rsqrtf(d) : 0.0f;
    }
}

// ---------------- GEMM: h[N,301] = x[N,978] @ W[978,301] ----------------
#define BM 64
#define BN 64
#define BK 16
__global__ __launch_bounds__(256) void gemm_xw(const float* __restrict__ x,
                                               const float* __restrict__ W,
                                               float* __restrict__ h) {
    __shared__ float As[BK][BM];  // [k][m], unpadded so float4 reads stay aligned
    __shared__ float Bs[BK][BN];
    const int bn = blockIdx.x * BN;
    const int bm = blockIdx.y * BM;
    const int tid = threadIdx.x;
    const int tm = (tid / 16) * 4;  // 16x16 thread grid, 4x4 micro-tile
    const int tn = (tid % 16) * 4;

    float acc[4][4] = {};

    for (int k0 = 0; k0 < NGENES; k0 += BK) {
        // load A tile: 64 rows x 16 k
        #pragma unroll
        for (int l = 0; l < 4; ++l) {
            int idx = tid + l * 256;
            int m = idx >> 4, k = idx & 15;
            int gr = bm + m, gk = k0 + k;
            As[k][m] = (gk < NGENES && gr < NNODES) ? x[(size_t)gr * NGENES + gk] : 0.0f;
        }
        // load B tile: 16 k x 64 cols
        #pragma unroll
        for (int l = 0; l < 4; ++l) {
            int idx = tid + l * 256;
            int k = idx >> 6, n = idx & 63;
            int gk = k0 + k, gn = bn + n;
            Bs[k][n] = (gk < NGENES && gn < EDIM) ? W[(size_t)gk * EDIM + gn] : 0.0f;
        }
        __syncthreads();
        #pragma unroll
        for (int k = 0; k < BK; ++k) {
            float4 a4 = *reinterpret_cast<const float4*>(&As[k][tm]);
            float4 b4 = *reinterpret_cast<const float4*>(&Bs[k][tn]);
            float a[4] = {a4.x, a4.y, a4.z, a4.w};
            float b[4] = {b4.x, b4.y, b4.z, b4.w};
            #pragma unroll
            for (int i = 0; i < 4; ++i)
                #pragma unroll
                for (int j = 0; j < 4; ++j) acc[i][j] = fmaf(a[i], b[j], acc[i][j]);
        }
        __syncthreads();
    }

    #pragma unroll
    for (int i = 0; i < 4; ++i) {
        int gr = bm + tm + i;
        if (gr >= NNODES) continue;
        #pragma unroll
        for (int j = 0; j < 4; ++j) {
            int gc = bn + tn + j;
            if (gc < EDIM) h[(size_t)gr * EDIM + gc] = acc[i][j];
        }
    }
}

// ---------------- self-loop init: out = h/deg + b ----------------
__global__ void init_out(const float* __restrict__ h, const float* __restrict__ deg,
                         const float* __restrict__ b, float* __restrict__ out) {
    int i = blockIdx.x * blockDim.x + threadIdx.x;
    if (i >= NNODES * EDIM) return;
    int n = i / EDIM;
    int c = i - n * EDIM;
    out[i] = h[i] / deg[n] + b[c];   // self-loop norm = dinv^2 = 1/deg
}

// ---------------- edge scatter: out[dst] += norm * h[src] ----------------
__global__ __launch_bounds__(256) void scatter_edges(const void* __restrict__ ei,
                                                     const float* __restrict__ w,
                                                     const float* __restrict__ dinv,
                                                     const float* __restrict__ h,
                                                     float* __restrict__ out,
                                                     const int* __restrict__ flag) {
    const int is64 = *flag;
    const int wid  = (blockIdx.x * blockDim.x + threadIdx.x) >> 6;
    const int lane = threadIdx.x & 63;
    const int nw   = (gridDim.x * blockDim.x) >> 6;
    for (int e = wid; e < NEDGES; e += nw) {
        int s = load_idx(ei, e, is64);
        int d = load_idx(ei, (long long)NEDGES + e, is64);
        float nrm = dinv[s] * w[e] * dinv[d];
        const float* hs = h + (size_t)s * EDIM;
        float* od = out + (size_t)d * EDIM;
        for (int j = lane; j < EDIM; j += 64) {
            atomicAdd(&od[j], nrm * hs[j]);
        }
    }
}

// ---------------- relu + broadcast to (N, 4, 301, 12) ----------------
__global__ __launch_bounds__(256) void bcast_out(const float* __restrict__ res,
                                                 float4* __restrict__ out) {
    int nh = blockIdx.x;          // n*4 + head
    int n = nh >> 2;
    const float* row = res + (size_t)n * EDIM;
    float4* orow = out + (size_t)nh * F4_PER_NH;
    for (int t = threadIdx.x; t < F4_PER_NH; t += 256) {
        int c = t / 3;
        float v = fmaxf(row[c], 0.0f);
        orow[t] = make_float4(v, v, v, v);
    }
}

// ---------------- launch ----------------
extern "C" void kernel_launch(void* const* d_in, const int* in_sizes, int n_in,
                              void* d_out, int out_size, void* d_ws, size_t ws_size,
                              hipStream_t stream) {
    const float* x  = (const float*)d_in[0];
    const void*  ei = d_in[1];                 // int32 or int64, detected on device
    const float* ew = (const float*)d_in[2];
    const float* W  = (const float*)d_in[3];
    const float* b  = (const float*)d_in[4];
    float* out = (float*)d_out;

    // workspace layout (floats)
    float* f       = (float*)d_ws;
    float* deg     = f;                        // 10000
    int*   flag    = (int*)(f + 10016);        // 1 int
    float* dinv    = f + 10240;                // 10000
    float* h       = f + 20480;                // 10000*301 = 3,010,000
    float* out_acc = h + (size_t)NNODES * EDIM;// 3,010,000
    // total ~24.2 MB

    detect_idx64<<<1, 64, 0, stream>>>((const unsigned int*)ei, flag);
    init_deg<<<(NNODES + 255) / 256, 256, 0, stream>>>(deg);
    accum_deg<<<(NEDGES + 255) / 256, 256, 0, stream>>>(ei, ew, deg, flag);
    compute_dinv<<<(NNODES + 255) / 256, 256, 0, stream>>>(deg, dinv);

    dim3 ggrid((EDIM + BN - 1) / BN, (NNODES + BM - 1) / BM);
    gemm_xw<<<ggrid, 256, 0, stream>>>(x, W, h);

    init_out<<<(NNODES * EDIM + 255) / 256, 256, 0, stream>>>(h, deg, b, out_acc);

    scatter_edges<<<2048, 256, 0, stream>>>(ei, ew, dinv, h, out_acc, flag);

    bcast_out<<<NNODES * NHEADS, 256, 0, stream>>>(out_acc, (float4*)d_out);
    (void)in_sizes; (void)n_in; (void)out_size; (void)ws_size; (void)out;
}

// Round 2
// 993.151 us; speedup vs baseline: 1.2551x; 1.2551x over previous
//
#include <hip/hip_runtime.h>
#include <math.h>

#define NGENES 978
#define EDIM   301
#define NNODES 10000
#define NEDGES 320000
#define NHEADS 4
#define REP    12            // 48/4 floats repeated per (n,h,c)

// ---------------- index dtype detection (int32 vs int64) ----------------
__global__ void detect_idx64(const unsigned int* __restrict__ ei, int* flag) {
    int lane = threadIdx.x;  // 64 threads
    unsigned int v = ei[2 * lane + 1];
    unsigned long long nz = __ballot(v != 0u);
    if (lane == 0) *flag = (nz == 0ULL) ? 1 : 0;
}

__device__ __forceinline__ int load_idx(const void* ei, long long i, int is64) {
    return is64 ? (int)((const long long*)ei)[i] : ((const int*)ei)[i];
}

// ---------------- init: deg=1 (self-loop), cnt=0, cur=0 ----------------
__global__ void init_counts(float* deg, int* cnt, int* cur) {
    int i = blockIdx.x * blockDim.x + threadIdx.x;
    if (i < NNODES) { deg[i] = 1.0f; cnt[i] = 0; cur[i] = 0; }
}

// ---------------- per-edge: deg += w, cnt++ ----------------
__global__ void accum_deg(const void* __restrict__ ei, const float* __restrict__ w,
                          float* deg, int* cnt, const int* __restrict__ flag) {
    int i = blockIdx.x * blockDim.x + threadIdx.x;
    if (i >= NEDGES) return;
    int is64 = *flag;
    int d = load_idx(ei, (long long)NEDGES + i, is64);
    atomicAdd(&deg[d], w[i]);
    atomicAdd(&cnt[d], 1);
}

__global__ void compute_dinv(const float* __restrict__ deg, float* dinv) {
    int i = blockIdx.x * blockDim.x + threadIdx.x;
    if (i < NNODES) {
        float d = deg[i];
        dinv[i] = (d > 0.0f) ? rsqrtf(d) : 0.0f;
    }
}

// ---------------- exclusive scan of cnt[10000] -> base (one block) ------
__global__ __launch_bounds__(1024) void scan_deg(const int* __restrict__ cnt,
                                                 int* __restrict__ base_) {
    __shared__ int part[1024];
    const int t = threadIdx.x;
    int local[10];
    int s = 0;
    #pragma unroll
    for (int j = 0; j < 10; ++j) {
        int idx = t * 10 + j;
        int v = (idx < NNODES) ? cnt[idx] : 0;
        local[j] = s;            // exclusive within chunk
        s += v;
    }
    part[t] = s;
    __syncthreads();
    for (int off = 1; off < 1024; off <<= 1) {
        int v = (t >= off) ? part[t - off] : 0;
        __syncthreads();
        part[t] += v;
        __syncthreads();
    }
    int carry = (t > 0) ? part[t - 1] : 0;
    #pragma unroll
    for (int j = 0; j < 10; ++j) {
        int idx = t * 10 + j;
        if (idx < NNODES) base_[idx] = carry + local[j];
    }
}

// ---------------- bucket fill: es/en grouped by dst ----------------
__global__ void fill_csr(const void* __restrict__ ei, const float* __restrict__ w,
                         const float* __restrict__ dinv, const int* __restrict__ base_,
                         int* cur, int* __restrict__ es, float* __restrict__ en,
                         const int* __restrict__ flag) {
    int e = blockIdx.x * blockDim.x + threadIdx.x;
    if (e >= NEDGES) return;
    int is64 = *flag;
    int s = load_idx(ei, e, is64);
    int d = load_idx(ei, (long long)NEDGES + e, is64);
    float nrm = dinv[s] * w[e] * dinv[d];
    int pos = base_[d] + atomicAdd(&cur[d], 1);
    es[pos] = s;
    en[pos] = nrm;
}

// ---------------- GEMM: h[N,301] = x[N,978] @ W[978,301] ----------------
// 128x64 tile, BK=16, 256 threads, 8x4 microtile (rows split 4+4, 64 apart)
#define BM 128
#define BN 64
#define BK 16
__global__ __launch_bounds__(256) void gemm_xw(const float* __restrict__ x,
                                               const float* __restrict__ W,
                                               float* __restrict__ h) {
    __shared__ float As[BK][BM];   // [k][m]
    __shared__ float Bs[BK][BN];   // [k][n]
    const int bn = blockIdx.x * BN;
    const int bm = blockIdx.y * BM;
    const int tid = threadIdx.x;
    const int m0 = (tid >> 4) * 4;      // 0..60, rows m0..m0+3 and m0+64..m0+67
    const int tn = (tid & 15) * 4;      // 0..60

    float acc[8][4] = {};

    for (int k0 = 0; k0 < NGENES; k0 += BK) {
        // A tile: 128 rows x 16 k. Thread: row = tid/2, k-offset = (tid&1)*8,
        // 4 x float2 along k (978 even -> rows 8B-aligned).
        {
            int ar = tid >> 1;
            int ak = (tid & 1) * 8;
            int gr = bm + ar;
            #pragma unroll
            for (int j = 0; j < 4; ++j) {
                int gk = k0 + ak + 2 * j;
                float2 v = make_float2(0.f, 0.f);
                if (gr < NNODES && gk + 1 < NGENES)
                    v = *reinterpret_cast<const float2*>(&x[(size_t)gr * NGENES + gk]);
                As[ak + 2 * j][ar]     = v.x;
                As[ak + 2 * j + 1][ar] = v.y;
            }
        }
        // B tile: 16 k x 64 n. Thread: k = tid/16, n4 = (tid&15)*4, scalar loads
        // (301-stride rows are not 16B aligned).
        {
            int bk = tid >> 4;
            int n4 = (tid & 15) * 4;
            int gk = k0 + bk;
            #pragma unroll
            for (int j = 0; j < 4; ++j) {
                int gn = bn + n4 + j;
                Bs[bk][n4 + j] = (gk < NGENES && gn < EDIM)
                                     ? W[(size_t)gk * EDIM + gn] : 0.0f;
            }
        }
        __syncthreads();
        #pragma unroll
        for (int k = 0; k < BK; ++k) {
            float4 alo = *reinterpret_cast<const float4*>(&As[k][m0]);
            float4 ahi = *reinterpret_cast<const float4*>(&As[k][m0 + 64]);
            float4 b4  = *reinterpret_cast<const float4*>(&Bs[k][tn]);
            float a[8] = {alo.x, alo.y, alo.z, alo.w, ahi.x, ahi.y, ahi.z, ahi.w};
            float b[4] = {b4.x, b4.y, b4.z, b4.w};
            #pragma unroll
            for (int i = 0; i < 8; ++i)
                #pragma unroll
                for (int j = 0; j < 4; ++j) acc[i][j] = fmaf(a[i], b[j], acc[i][j]);
        }
        __syncthreads();
    }

    #pragma unroll
    for (int i = 0; i < 8; ++i) {
        int gr = bm + ((i < 4) ? (m0 + i) : (64 + m0 + i - 4));
        if (gr >= NNODES) continue;
        #pragma unroll
        for (int j = 0; j < 4; ++j) {
            int gc = bn + tn + j;
            if (gc < EDIM) h[(size_t)gr * EDIM + gc] = acc[i][j];
        }
    }
}

// ---------------- fused gather + self-loop + bias + relu + broadcast ----
// One block per dst node. Thread t accumulates channels t and t+256.
__global__ __launch_bounds__(256) void gather_out(const float* __restrict__ h,
                                                  const float* __restrict__ deg,
                                                  const float* __restrict__ bias,
                                                  const int* __restrict__ es,
                                                  const float* __restrict__ en,
                                                  const int* __restrict__ base_,
                                                  const int* __restrict__ cnt,
                                                  float4* __restrict__ out) {
    __shared__ int   s_src[256];
    __shared__ float s_nrm[256];
    const int n = blockIdx.x;
    const int t = threadIdx.x;
    const int c0 = t;
    const int c1 = t + 256;

    const float inv_deg = 1.0f / deg[n];   // self-loop norm (deg >= 1 always)
    float acc0 = (c0 < EDIM) ? h[(size_t)n * EDIM + c0] * inv_deg + bias[c0] : 0.0f;
    float acc1 = (c1 < EDIM) ? h[(size_t)n * EDIM + c1] * inv_deg + bias[c1] : 0.0f;

    const int cnt_n = cnt[n];
    const int b0 = base_[n];
    for (int e0 = 0; e0 < cnt_n; e0 += 256) {
        int m = min(256, cnt_n - e0);
        if (t < m) { s_src[t] = es[b0 + e0 + t]; s_nrm[t] = en[b0 + e0 + t]; }
        __syncthreads();
        for (int e = 0; e < m; ++e) {
            int s = s_src[e];
            float nr = s_nrm[e];
            const float* hs = h + (size_t)s * EDIM;
            if (c0 < EDIM) acc0 += nr * hs[c0];
            if (c1 < EDIM) acc1 += nr * hs[c1];
        }
        __syncthreads();
    }

    acc0 = fmaxf(acc0, 0.0f);
    acc1 = fmaxf(acc1, 0.0f);

    // out[n][head][c][0..11]; 12 floats = 3 float4, base offsets all 16B-aligned
    #pragma unroll
    for (int head = 0; head < NHEADS; ++head) {
        float4* orow = out + ((size_t)(n * NHEADS + head) * EDIM * 3);
        if (c0 < EDIM) {
            float4 v = make_float4(acc0, acc0, acc0, acc0);
            orow[c0 * 3]     = v;
            orow[c0 * 3 + 1] = v;
            orow[c0 * 3 + 2] = v;
        }
        if (c1 < EDIM) {
            float4 v = make_float4(acc1, acc1, acc1, acc1);
            orow[c1 * 3]     = v;
            orow[c1 * 3 + 1] = v;
            orow[c1 * 3 + 2] = v;
        }
    }
}

// ---------------- launch ----------------
extern "C" void kernel_launch(void* const* d_in, const int* in_sizes, int n_in,
                              void* d_out, int out_size, void* d_ws, size_t ws_size,
                              hipStream_t stream) {
    const float* x  = (const float*)d_in[0];
    const void*  ei = d_in[1];                 // int32 or int64, detected on device
    const float* ew = (const float*)d_in[2];
    const float* W  = (const float*)d_in[3];
    const float* b  = (const float*)d_in[4];

    // workspace layout (4-byte units)
    float* f    = (float*)d_ws;
    float* deg  = f;                            // 10000
    float* dinv = f + 10240;                    // 10000
    int*   cnt  = (int*)(f + 20480);            // 10000
    int*   base_= (int*)(f + 30720);            // 10000
    int*   cur  = (int*)(f + 40960);            // 10000
    int*   flag = (int*)(f + 51200);            // 1
    int*   es   = (int*)(f + 51456);            // 320000
    float* en   = f + 51456 + 320000;           // 320000
    float* h    = en + 320000;                  // 3,010,000
    // total ~15.6 MB

    detect_idx64<<<1, 64, 0, stream>>>((const unsigned int*)ei, flag);
    init_counts<<<(NNODES + 255) / 256, 256, 0, stream>>>(deg, cnt, cur);
    accum_deg<<<(NEDGES + 255) / 256, 256, 0, stream>>>(ei, ew, deg, cnt, flag);
    compute_dinv<<<(NNODES + 255) / 256, 256, 0, stream>>>(deg, dinv);
    scan_deg<<<1, 1024, 0, stream>>>(cnt, base_);
    fill_csr<<<(NEDGES + 255) / 256, 256, 0, stream>>>(ei, ew, dinv, base_, cur, es, en, flag);

    dim3 ggrid((EDIM + BN - 1) / BN, (NNODES + BM - 1) / BM);
    gemm_xw<<<ggrid, 256, 0, stream>>>(x, W, h);

    gather_out<<<NNODES, 256, 0, stream>>>(h, deg, b, es, en, base_, cnt, (float4*)d_out);
    (void)in_sizes; (void)n_in; (void)out_size; (void)ws_size;
}

// Round 3
// 763.831 us; speedup vs baseline: 1.6319x; 1.3002x over previous
//
#include <hip/hip_runtime.h>
#include <math.h>

#define NGENES 978
#define EDIM   301
#define NNODES 10000
#define NEDGES 320000
#define KPAD   992      // 31*32 (K padded for MFMA)
#define NPAD   320      // 5*64  (N padded)
#define MPAD   10112    // 79*128 (M padded)

typedef float f4v __attribute__((ext_vector_type(4)));
typedef short s8v __attribute__((ext_vector_type(8)));

// ---------------- bf16 split: v ~= hi + lo (truncation split) ----------------
__device__ __forceinline__ void split_bf16(float v, short& hi, short& lo) {
    unsigned int b = __float_as_uint(v);
    hi = (short)(b >> 16);
    float hif = __uint_as_float(b & 0xFFFF0000u);
    float lof = v - hif;               // exact
    lo = (short)(__float_as_uint(lof) >> 16);
}

// ---------------- prep: init deg/cnt/cur + detect idx dtype ----------------
__global__ void prep_init(const unsigned int* __restrict__ ei, int* flag,
                          float* deg, int* cnt, int* cur) {
    int i = blockIdx.x * blockDim.x + threadIdx.x;
    if (i < NNODES) { deg[i] = 1.0f; cnt[i] = 0; cur[i] = 0; }
    if (blockIdx.x == 0 && threadIdx.x < 64) {
        // int64 edge_index (values < 2^31) => all odd 32-bit words zero
        unsigned int v = ei[2 * threadIdx.x + 1];
        unsigned long long nz = __ballot(v != 0u);
        if (threadIdx.x == 0) *flag = (nz == 0ULL) ? 1 : 0;
    }
}

__device__ __forceinline__ int load_idx(const void* ei, long long i, int is64) {
    return is64 ? (int)((const long long*)ei)[i] : ((const int*)ei)[i];
}

// ---------------- per-edge: deg += w, cnt++ ----------------
__global__ void accum_deg(const void* __restrict__ ei, const float* __restrict__ w,
                          float* deg, int* cnt, const int* __restrict__ flag) {
    int i = blockIdx.x * blockDim.x + threadIdx.x;
    if (i >= NEDGES) return;
    int is64 = *flag;
    int d = load_idx(ei, (long long)NEDGES + i, is64);
    atomicAdd(&deg[d], w[i]);
    atomicAdd(&cnt[d], 1);
}

// ---------------- scan cnt -> base, plus dinv = rsqrt(deg) ----------------
__global__ __launch_bounds__(1024) void scan_dinv(const int* __restrict__ cnt,
                                                  int* __restrict__ base_,
                                                  const float* __restrict__ deg,
                                                  float* __restrict__ dinv) {
    __shared__ int part[1024];
    const int t = threadIdx.x;
    int local[10];
    int s = 0;
    #pragma unroll
    for (int j = 0; j < 10; ++j) {
        int idx = t * 10 + j;
        int v = (idx < NNODES) ? cnt[idx] : 0;
        local[j] = s;
        s += v;
    }
    part[t] = s;
    __syncthreads();
    for (int off = 1; off < 1024; off <<= 1) {
        int v = (t >= off) ? part[t - off] : 0;
        __syncthreads();
        part[t] += v;
        __syncthreads();
    }
    int carry = (t > 0) ? part[t - 1] : 0;
    #pragma unroll
    for (int j = 0; j < 10; ++j) {
        int idx = t * 10 + j;
        if (idx < NNODES) {
            base_[idx] = carry + local[j];
            float d = deg[idx];
            dinv[idx] = (d > 0.0f) ? rsqrtf(d) : 0.0f;
        }
    }
}

// ---------------- bucket fill: es/en grouped by dst ----------------
__global__ void fill_csr(const void* __restrict__ ei, const float* __restrict__ w,
                         const float* __restrict__ dinv, const int* __restrict__ base_,
                         int* cur, int* __restrict__ es, float* __restrict__ en,
                         const int* __restrict__ flag) {
    int e = blockIdx.x * blockDim.x + threadIdx.x;
    if (e >= NEDGES) return;
    int is64 = *flag;
    int s = load_idx(ei, e, is64);
    int d = load_idx(ei, (long long)NEDGES + e, is64);
    float nrm = dinv[s] * w[e] * dinv[d];
    int pos = base_[d] + atomicAdd(&cur[d], 1);
    es[pos] = s;
    en[pos] = nrm;
}

// ---------------- convert x[10000][978] -> xh/xl [10000][992] bf16 ----------
__global__ void cvt_x(const float* __restrict__ x, short* __restrict__ xh,
                      short* __restrict__ xl) {
    int idx = blockIdx.x * blockDim.x + threadIdx.x;   // over 10000 * 124
    if (idx >= NNODES * (KPAD / 8)) return;
    int r = idx / (KPAD / 8);
    int kc = (idx - r * (KPAD / 8)) * 8;
    s8v h8, l8;
    #pragma unroll
    for (int j = 0; j < 8; ++j) {
        int k = kc + j;
        float v = (k < NGENES) ? x[(size_t)r * NGENES + k] : 0.0f;
        short hi, lo;
        split_bf16(v, hi, lo);
        h8[j] = hi; l8[j] = lo;
    }
    *(s8v*)(xh + (size_t)r * KPAD + kc) = h8;
    *(s8v*)(xl + (size_t)r * KPAD + kc) = l8;
}

// ---------------- convert W[978][301] -> W^T hi/lo [320][992] bf16 ----------
__global__ void cvt_w(const float* __restrict__ W, short* __restrict__ wh,
                      short* __restrict__ wl) {
    int idx = blockIdx.x * blockDim.x + threadIdx.x;   // over 320 * 124
    if (idx >= NPAD * (KPAD / 8)) return;
    int n = idx / (KPAD / 8);
    int kc = (idx - n * (KPAD / 8)) * 8;
    s8v h8, l8;
    #pragma unroll
    for (int j = 0; j < 8; ++j) {
        int k = kc + j;
        float v = (n < EDIM && k < NGENES) ? W[(size_t)k * EDIM + n] : 0.0f;
        short hi, lo;
        split_bf16(v, hi, lo);
        h8[j] = hi; l8[j] = lo;
    }
    *(s8v*)(wh + (size_t)n * KPAD + kc) = h8;
    *(s8v*)(wl + (size_t)n * KPAD + kc) = l8;
}

// ---------------- MFMA GEMM: h[N,301] = x @ W (bf16 3-pass split) -----------
// 128x64 block tile, 4 waves (2x2), wave tile 64x32, BK=32.
// LDS rows padded to 40 shorts (80 B) -> <=2-way bank aliasing on b128 reads.
__global__ __launch_bounds__(256) void gemm_bf16(const short* __restrict__ xh,
                                                 const short* __restrict__ xl,
                                                 const short* __restrict__ wh,
                                                 const short* __restrict__ wl,
                                                 float* __restrict__ h) {
    __shared__ short Ah[128 * 40], Al[128 * 40], Bh[64 * 40], Bl[64 * 40];
    const int tid  = threadIdx.x;
    const int lane = tid & 63;
    const int w    = tid >> 6;
    const int wm   = (w >> 1) * 64;
    const int wn   = (w & 1) * 32;
    const int bm   = blockIdx.y * 128;
    const int bn   = blockIdx.x * 64;
    const int l15  = lane & 15;
    const int g8   = (lane >> 4) * 8;    // k offset (shorts) of this lane group

    f4v acc[4][2] = {};

    const int arow0 = tid >> 2;          // 0..63
    const int aslot = (tid & 3) * 8;     // 0,8,16,24

    for (int ks = 0; ks < KPAD / 32; ++ks) {
        const int k0 = ks * 32;
        // stage A (128 rows x 32 k, hi+lo)
        #pragma unroll
        for (int q = 0; q < 2; ++q) {
            const int row = q * 64 + arow0;
            const size_t goff = (size_t)(bm + row) * KPAD + k0 + aslot;
            s8v vh = *(const s8v*)(xh + goff);
            s8v vl = *(const s8v*)(xl + goff);
            *(s8v*)&Ah[row * 40 + aslot] = vh;
            *(s8v*)&Al[row * 40 + aslot] = vl;
        }
        // stage B (64 rows(n) x 32 k, hi+lo)
        {
            const int row = tid >> 2;    // 0..63
            const size_t goff = (size_t)(bn + row) * KPAD + k0 + aslot;
            s8v vh = *(const s8v*)(wh + goff);
            s8v vl = *(const s8v*)(wl + goff);
            *(s8v*)&Bh[row * 40 + aslot] = vh;
            *(s8v*)&Bl[row * 40 + aslot] = vl;
        }
        __syncthreads();
        s8v ah[4], al[4], bh[2], bl[2];
        #pragma unroll
        for (int fn = 0; fn < 2; ++fn) {
            const int r = wn + fn * 16 + l15;
            bh[fn] = *(const s8v*)&Bh[r * 40 + g8];
            bl[fn] = *(const s8v*)&Bl[r * 40 + g8];
        }
        #pragma unroll
        for (int fm = 0; fm < 4; ++fm) {
            const int r = wm + fm * 16 + l15;
            ah[fm] = *(const s8v*)&Ah[r * 40 + g8];
            al[fm] = *(const s8v*)&Al[r * 40 + g8];
        }
        #pragma unroll
        for (int fm = 0; fm < 4; ++fm)
            #pragma unroll
            for (int fn = 0; fn < 2; ++fn) {
                acc[fm][fn] = __builtin_amdgcn_mfma_f32_16x16x32_bf16(ah[fm], bh[fn], acc[fm][fn], 0, 0, 0);
                acc[fm][fn] = __builtin_amdgcn_mfma_f32_16x16x32_bf16(ah[fm], bl[fn], acc[fm][fn], 0, 0, 0);
                acc[fm][fn] = __builtin_amdgcn_mfma_f32_16x16x32_bf16(al[fm], bh[fn], acc[fm][fn], 0, 0, 0);
            }
        __syncthreads();
    }
    // C write: D col = lane&15 (n), row = (lane>>4)*4 + reg (m)
    const int mrb = (lane >> 4) * 4;
    #pragma unroll
    for (int fm = 0; fm < 4; ++fm)
        #pragma unroll
        for (int fn = 0; fn < 2; ++fn) {
            const int col = bn + wn + fn * 16 + l15;
            if (col >= EDIM) continue;
            #pragma unroll
            for (int r = 0; r < 4; ++r) {
                const int row = bm + wm + fm * 16 + mrb + r;
                if (row < NNODES) h[(size_t)row * EDIM + col] = acc[fm][fn][r];
            }
        }
}

// ------- fused gather + self-loop + bias + relu + coalesced broadcast -------
// One block (320 threads = 5 waves) per dst node; thread t owns channel t.
__global__ __launch_bounds__(320) void gather_out(const float* __restrict__ h,
                                                  const float* __restrict__ dinv,
                                                  const float* __restrict__ bias,
                                                  const int* __restrict__ es,
                                                  const float* __restrict__ en,
                                                  const int* __restrict__ base_,
                                                  const int* __restrict__ cnt,
                                                  float4* __restrict__ out) {
    __shared__ int   s_src[64];
    __shared__ float s_nrm[64];
    __shared__ float row[EDIM];
    const int n = blockIdx.x;
    const int t = threadIdx.x;
    const int ce = (t < EDIM) ? t : 0;

    const float dn = dinv[n];
    float acc = h[(size_t)n * EDIM + ce] * (dn * dn) + bias[ce]; // self-loop: 1/deg

    const int cnt_n = cnt[n];
    const int b0 = base_[n];
    for (int e0 = 0; e0 < cnt_n; e0 += 64) {
        const int m = min(64, cnt_n - e0);
        if (t < m) { s_src[t] = es[b0 + e0 + t]; s_nrm[t] = en[b0 + e0 + t]; }
        __syncthreads();
        int e = 0;
        for (; e + 4 <= m; e += 4) {
            int   s0 = s_src[e],     s1 = s_src[e + 1], s2 = s_src[e + 2], s3 = s_src[e + 3];
            float w0 = s_nrm[e],     w1 = s_nrm[e + 1], w2 = s_nrm[e + 2], w3 = s_nrm[e + 3];
            float v0 = h[(size_t)s0 * EDIM + ce];
            float v1 = h[(size_t)s1 * EDIM + ce];
            float v2 = h[(size_t)s2 * EDIM + ce];
            float v3 = h[(size_t)s3 * EDIM + ce];
            acc = fmaf(w0, v0, acc); acc = fmaf(w1, v1, acc);
            acc = fmaf(w2, v2, acc); acc = fmaf(w3, v3, acc);
        }
        for (; e < m; ++e) acc = fmaf(s_nrm[e], h[(size_t)s_src[e] * EDIM + ce], acc);
        __syncthreads();
    }

    if (t < EDIM) row[t] = fmaxf(acc, 0.0f);
    __syncthreads();

    // out[n][head][c][0..11] = 4 heads x 903 float4; coalesced lane-contiguous
    float4* o = out + (size_t)n * 4 * 903;
    for (int p = t; p < 903; p += 320) {
        const float v = row[p / 3];
        const float4 vv = make_float4(v, v, v, v);
        o[p] = vv; o[903 + p] = vv; o[1806 + p] = vv; o[2709 + p] = vv;
    }
}

// ---------------- launch ----------------
extern "C" void kernel_launch(void* const* d_in, const int* in_sizes, int n_in,
                              void* d_out, int out_size, void* d_ws, size_t ws_size,
                              hipStream_t stream) {
    const float* x  = (const float*)d_in[0];
    const void*  ei = d_in[1];
    const float* ew = (const float*)d_in[2];
    const float* W  = (const float*)d_in[3];
    const float* b  = (const float*)d_in[4];

    // workspace layout (byte offsets, 256B-aligned chunks)
    char* p = (char*)d_ws;
    float* deg  = (float*)p;                 p += 40960;
    float* dinv = (float*)p;                 p += 40960;
    int*   cnt  = (int*)p;                   p += 40960;
    int*   base_= (int*)p;                   p += 40960;
    int*   cur  = (int*)p;                   p += 40960;
    int*   flag = (int*)p;                   p += 256;
    int*   es   = (int*)p;                   p += (size_t)NEDGES * 4;
    float* en   = (float*)p;                 p += (size_t)NEDGES * 4;
    float* h    = (float*)p;                 p += (size_t)NNODES * EDIM * 4;
    short* xh   = (short*)p;                 p += (size_t)MPAD * KPAD * 2;
    short* xl   = (short*)p;                 p += (size_t)MPAD * KPAD * 2;
    short* wh   = (short*)p;                 p += (size_t)NPAD * KPAD * 2;
    short* wl   = (short*)p;                 p += (size_t)NPAD * KPAD * 2;
    // total ~56 MB

    prep_init<<<40, 256, 0, stream>>>((const unsigned int*)ei, flag, deg, cnt, cur);
    accum_deg<<<(NEDGES + 255) / 256, 256, 0, stream>>>(ei, ew, deg, cnt, flag);
    scan_dinv<<<1, 1024, 0, stream>>>(cnt, base_, deg, dinv);
    fill_csr<<<(NEDGES + 255) / 256, 256, 0, stream>>>(ei, ew, dinv, base_, cur, es, en, flag);

    cvt_x<<<(NNODES * (KPAD / 8) + 255) / 256, 256, 0, stream>>>(x, xh, xl);
    cvt_w<<<(NPAD * (KPAD / 8) + 255) / 256, 256, 0, stream>>>(W, wh, wl);

    dim3 ggrid(NPAD / 64, MPAD / 128);
    gemm_bf16<<<ggrid, 256, 0, stream>>>(xh, xl, wh, wl, h);

    gather_out<<<NNODES, 320, 0, stream>>>(h, dinv, b, es, en, base_, cnt, (float4*)d_out);
    (void)in_sizes; (void)n_in; (void)out_size; (void)ws_size;
}